// Round 9
// baseline (259.668 us; speedup 1.0000x reference)
//
#include <hip/hip_runtime.h>
#include <hip/hip_bf16.h>
#include <stdint.h>

#define MD   128
#define LBAS 256

// ws layout: NkFull fp32 (256x128) @0, Mbf bf16 (128x128) @131072
#define MBF_OFF 131072ull
#define WS_NEED (131072ull + 32768ull)

typedef __attribute__((ext_vector_type(8))) __bf16 bf16x8;
typedef __attribute__((ext_vector_type(4))) float floatx4;
typedef __attribute__((ext_vector_type(8))) unsigned short ushortx8;
typedef __attribute__((ext_vector_type(4))) unsigned short ushortx4;

__device__ __forceinline__ float bf2f(unsigned short u){
  union { unsigned int i; float f; } v; v.i = ((unsigned int)u) << 16; return v.f;
}
__device__ __forceinline__ unsigned short f2bf(float x){
  union { float f; unsigned int i; } v; v.f = x;
  unsigned int r = v.i + 0x7FFFu + ((v.i >> 16) & 1u);
  return (unsigned short)(r >> 16);
}
__device__ __forceinline__ int detect_f32(const void* Bbasis){
  return ((const unsigned int*)Bbasis)[0] == 0x3F800000u;   // cos(pi)^4 == 1.0f
}

// lgkm-only barrier: orders LDS cross-wave WITHOUT draining vmcnt, so
// in-flight global prefetch loads survive the barrier (unlike __syncthreads,
// which emits s_waitcnt vmcnt(0) lgkmcnt(0)). sched_barrier(0) fences pin
// code motion around it. All vmem deps in this kernel are same-wave
// (prefetch->S-write, compiler-tracked) or store-only (epilogue, disjoint).
__device__ __forceinline__ void bar_lgkm(){
  __builtin_amdgcn_sched_barrier(0);
  asm volatile("s_waitcnt lgkmcnt(0)" ::: "memory");
  __builtin_amdgcn_s_barrier();
  __builtin_amdgcn_sched_barrier(0);
}

// ================= K0: Nk table + M->bf16 =================
__global__ __launch_bounds__(256) void nk2_kernel(const void* __restrict__ Acoeff,
                                                  const void* __restrict__ Bbasis,
                                                  const void* __restrict__ Mmat,
                                                  float* __restrict__ NkFull,
                                                  unsigned short* __restrict__ Mbf){
  int gid = blockIdx.x * 256 + threadIdx.x;
  const int isf = detect_f32(Bbasis);
  if (gid < LBAS * MD){
    int idx = gid >> 7, j = gid & 127;
    float a, b;
    if (isf){ a = ((const float*)Acoeff)[j*LBAS+idx]; b = ((const float*)Bbasis)[idx*MD+j]; }
    else    { a = bf2f(((const unsigned short*)Acoeff)[j*LBAS+idx]);
              b = bf2f(((const unsigned short*)Bbasis)[idx*MD+j]); }
    NkFull[gid] = a * b;
  } else {
    int m = gid - LBAS * MD;
    if (m < MD * MD){
      Mbf[m] = isf ? f2bf(((const float*)Mmat)[m]) : ((const unsigned short*)Mmat)[m];
    }
  }
}

// ================= K1: fused pool(2^4) + GEMM + epilogue =================
// R1 (87us) dataflow with verified simplifications (prv-in-regs, sNk-once,
// separate Ct, Ct-coalesced epilogue) and ONE experimental change:
// all __syncthreads() replaced by lgkm-only barriers (bar_lgkm), so the
// per-iteration prefetch is NOT drained at the barrier and stays in flight
// through pool+MFMA+epilogue (a full iteration of overlap).
// LDS = 16896(S) + 8448(Ct) + 4352(Ab) + 8192(sNk) = 37888 B -> 4 blocks/CU.
__global__ __launch_bounds__(256, 4) void mega_kernel(const void* __restrict__ vec,
                                                      const float* __restrict__ NkFull,
                                                      const unsigned short* __restrict__ Mbf,
                                                      const void* __restrict__ Bbasis,
                                                      void* __restrict__ out){
  __shared__ __align__(16) float S[32 * 132];                  // staging (x2-pair sums)
  __shared__ __align__(16) float Ct[16 * 132];                 // MFMA output transpose
  __shared__ __align__(16) unsigned short Ab[16 * 136];        // A-tile (row 15 zeroed)
  __shared__ __align__(16) float sNk[16 * 128];                // j1 x j4 Nk rows

  // --- block decode: XCD-group same-b blocks (xcd = bid&7 -> {2b,2b+1}) ---
  const int xcd  = blockIdx.x & 7;
  const int slot = blockIdx.x >> 3;
  const int b    = xcd >> 1;
  const int s    = slot * 2 + (xcd & 1);
  if (s >= 225) return;
  const int w3 = s / 15;
  const int w2 = s - w3 * 15;
  const int t  = threadIdx.x;
  const int isf = detect_f32(Bbasis);

  const int wave = t >> 6, lane = t & 63;
  const int quad = lane >> 4, l16 = lane & 15;

  // vec strides (elems): b 8388608, x1 524288, x2 32768, x3 2048, x4 128
  const size_t vbase0 = (size_t)b * 8388608 + (size_t)w2 * 32768 + (size_t)w3 * 2048;

  // --- per-thread static offsets ---
  int offF[4];   // fp32: 4 float4-chunks
#pragma unroll
  for (int k = 0; k < 4; ++k){
    const int ci = k * 256 + t;          // 0..1023
    const int row = ci >> 5;             // x3sub*16 + x4
    offF[k] = (row >> 4) * 2048 + (row & 15) * 128 + (ci & 31) * 4;
  }
  int offB[2];   // bf16: 2 ushortx8-chunks
#pragma unroll
  for (int k = 0; k < 2; ++k){
    const int ci = k * 256 + t;          // 0..511
    const int row = ci >> 4;
    offB[k] = (row >> 4) * 2048 + (row & 15) * 128 + (ci & 15) * 8;
  }

  floatx4 pre[4][2];   // prefetch regs (bf16 path bit-casts into pre[0..1])

  // --- prefetch x1 = 0 (issue HBM loads first) ---
  if (isf){
    const float* vf = (const float*)vec + vbase0;
#pragma unroll
    for (int k = 0; k < 4; ++k){
      pre[k][0] = *(const floatx4*)(vf + offF[k]);
      pre[k][1] = *(const floatx4*)(vf + offF[k] + 32768);
    }
  } else {
    const unsigned short* vh = (const unsigned short*)vec + vbase0;
#pragma unroll
    for (int k = 0; k < 2; ++k){
      *(ushortx8*)&pre[k][0] = *(const ushortx8*)(vh + offB[k]);
      *(ushortx8*)&pre[k][1] = *(const ushortx8*)(vh + offB[k] + 32768);
    }
  }

  // --- M fragments -> registers (loop-invariant; 16 VGPRs; L2-hot source) ---
  bf16x8 mfr[2][4];
#pragma unroll
  for (int cc = 0; cc < 2; ++cc)
#pragma unroll
    for (int s4 = 0; s4 < 4; ++s4)
      *(ushortx8*)&mfr[cc][s4] =
          *(const ushortx8*)(Mbf + ((wave * 2 + cc) * 16 + l16) * 128 + s4 * 32 + quad * 8);

  // --- stage the 16 Nk rows (j1 x j4) once; zero Ab row 15 ---
  {
    const int j2f = (w2 & 3), j3f = (w3 & 3);
#pragma unroll
    for (int k = 0; k < 2; ++k){
      const int ci = k * 256 + t;            // 0..511 float4 chunks
      const int row16 = ci >> 5, c4 = (ci & 31) * 4;
      const int j1 = row16 >> 2, j4 = row16 & 3;
      const int nkrow = ((j1 * 4 + j2f) * 4 + j3f) * 4 + j4;
      *(floatx4*)&sNk[row16 * 128 + c4] = *(const floatx4*)&NkFull[nkrow * 128 + c4];
    }
    if (t >= 240){                            // zero A-tile row 15 (D row 15 discarded)
      const ushortx8 z = (ushortx8){0,0,0,0,0,0,0,0};
      *(ushortx8*)&Ab[15 * 136 + (t & 15) * 8] = z;
    }
  }

  const int pw4 = t >> 4;            // pooling coords (t<240 active)
  const int pc8 = (t & 15) * 8;
  const int owner = (t < 240);
  float prv[8];                      // per-thread pooled history (in regs)

  for (int x1 = 0; x1 < 16; ++x1){
    // ---- regs -> S (x2-pair sum); compiler inserts vmcnt for pre use ----
    if (isf){
#pragma unroll
      for (int k = 0; k < 4; ++k){
        const int ci = k * 256 + t;
        const int row = ci >> 5, c4 = (ci & 31) * 4;
        floatx4 sv;
#pragma unroll
        for (int q = 0; q < 4; ++q) sv[q] = pre[k][0][q] + pre[k][1][q];
        *(floatx4*)&S[row * 132 + c4] = sv;
      }
    } else {
#pragma unroll
      for (int k = 0; k < 2; ++k){
        const int ci = k * 256 + t;
        const int row = ci >> 4, c8 = (ci & 15) * 8;
        const ushortx8 a = *(const ushortx8*)&pre[k][0];
        const ushortx8 c = *(const ushortx8*)&pre[k][1];
#pragma unroll
        for (int q = 0; q < 8; ++q) S[row * 132 + c8 + q] = bf2f(a[q]) + bf2f(c[q]);
      }
    }

    // ---- prefetch x1+1 (issued here; survives lgkm-only barriers below,
    //      hidden under pool+MFMA+epilogue of this iteration) ----
    if (x1 < 15){
      if (isf){
        const float* vf = (const float*)vec + vbase0 + (size_t)(x1 + 1) * 524288;
#pragma unroll
        for (int k = 0; k < 4; ++k){
          pre[k][0] = *(const floatx4*)(vf + offF[k]);
          pre[k][1] = *(const floatx4*)(vf + offF[k] + 32768);
        }
      } else {
        const unsigned short* vh = (const unsigned short*)vec + vbase0 + (size_t)(x1 + 1) * 524288;
#pragma unroll
        for (int k = 0; k < 2; ++k){
          *(ushortx8*)&pre[k][0] = *(const ushortx8*)(vh + offB[k]);
          *(ushortx8*)&pre[k][1] = *(const ushortx8*)(vh + offB[k] + 32768);
        }
      }
    }
    bar_lgkm();   // bar B: S visible; prefetch stays in flight

    // ---- pool x3,x4 (2x2) vectorized + A-tile build; history in regs ----
    if (owner){
      const int p0 = pw4 * 132 + pc8;
      const floatx4 a0 = *(const floatx4*)&S[p0];
      const floatx4 a1 = *(const floatx4*)&S[p0 + 4];
      const floatx4 b0 = *(const floatx4*)&S[p0 + 132];
      const floatx4 b1 = *(const floatx4*)&S[p0 + 136];
      const floatx4 c0 = *(const floatx4*)&S[p0 + 16 * 132];
      const floatx4 c1 = *(const floatx4*)&S[p0 + 16 * 132 + 4];
      const floatx4 d0 = *(const floatx4*)&S[p0 + 17 * 132];
      const floatx4 d1 = *(const floatx4*)&S[p0 + 17 * 132 + 4];
      float cur[8];
      const floatx4 lo = ((a0 + b0) + (c0 + d0)) * 0.125f;
      const floatx4 hi = ((a1 + b1) + (c1 + d1)) * 0.125f;
#pragma unroll
      for (int e = 0; e < 4; ++e){ cur[e] = lo[e]; cur[4 + e] = hi[e]; }
      if (x1 > 0){
        ushortx8 av;
#pragma unroll
        for (int e = 0; e < 8; ++e) av[e] = f2bf((cur[e] + prv[e]) * 0.5f);
        *(ushortx8*)&Ab[pw4 * 136 + pc8] = av;
      }
#pragma unroll
      for (int e = 0; e < 8; ++e) prv[e] = cur[e];
    }
    bar_lgkm();   // bar C: Ab visible; S reads done (next S-write safe)

    if (x1 > 0){
      // ---- MFMA: wave w -> col tiles {2w, 2w+1}; B from registers ----
      floatx4 acc[2];
      acc[0] = (floatx4){0.f,0.f,0.f,0.f};
      acc[1] = (floatx4){0.f,0.f,0.f,0.f};
#pragma unroll
      for (int s4 = 0; s4 < 4; ++s4){
        const bf16x8 af = *(const bf16x8*)&Ab[l16 * 136 + s4 * 32 + quad * 8];
#pragma unroll
        for (int cc = 0; cc < 2; ++cc){
          acc[cc] = __builtin_amdgcn_mfma_f32_16x16x32_bf16(af, mfr[cc][s4], acc[cc], 0, 0, 0);
        }
      }
      // ---- transpose via Ct (separate buffer) ----
#pragma unroll
      for (int cc = 0; cc < 2; ++cc)
#pragma unroll
        for (int reg = 0; reg < 4; ++reg)
          Ct[(quad * 4 + reg) * 132 + (wave * 2 + cc) * 16 + l16] = acc[cc][reg];
      bar_lgkm();   // bar D: Ct visible; Ab reads done (next Ab write safe)

      // ---- epilogue: 15 rows x 512 B contiguous stores ----
      const int w1 = x1 - 1;
      const int j1sel = w1 & 3;
      const size_t outBase = ((size_t)(((b * 15 + w1) * 15 + w2) * 15 + w3)) * 15;
#pragma unroll
      for (int k = 0; k < 2; ++k){
        const int ci = k * 256 + t;
        if (ci < 480){
          const int row = ci >> 5, c4 = (ci & 31) * 4;
          const floatx4 v  = *(const floatx4*)&Ct[row * 132 + c4];
          const floatx4 nk = *(const floatx4*)&sNk[(j1sel * 4 + (row & 3)) * 128 + c4];
          floatx4 o;
#pragma unroll
          for (int e = 0; e < 4; ++e) o[e] = nk[e] - v[e];
          if (isf){
            *(floatx4*)((float*)out + (outBase + row) * 128 + c4) = o;
          } else {
            ushortx4 ob;
#pragma unroll
            for (int e = 0; e < 4; ++e) ob[e] = f2bf(o[e]);
            *(ushortx4*)((unsigned short*)out + (outBase + row) * 128 + c4) = ob;
          }
        }
      }
    }
  }
}

extern "C" void kernel_launch(void* const* d_in, const int* in_sizes, int n_in,
                              void* d_out, int out_size, void* d_ws, size_t ws_size,
                              hipStream_t stream) {
  const void* vec = d_in[0];   // (4,16,16,16,16,128)
  const void* Mm  = d_in[1];   // (128,128)
  const void* Ac  = d_in[2];   // (128,256)
  const void* Bb  = d_in[3];   // (256,128)

  float* NkFull = (float*)d_ws;
  unsigned short* Mbf = (unsigned short*)((char*)d_ws + MBF_OFF);

  nk2_kernel<<<192, 256, 0, stream>>>(Ac, Bb, Mm, NkFull, Mbf);
  mega_kernel<<<904, 256, 0, stream>>>(vec, NkFull, Mbf, Bb, d_out);
}